// Round 1
// baseline (837.812 us; speedup 1.0000x reference)
//
#include <hip/hip_runtime.h>

#define N_NODES 100000
#define N_EDGES 1600000
#define DIN 128
#define DOUT 128
#define NH 4
#define DH 32
#define EPS 1e-9f

// ---------------- K1: build concatenated weight matrix Wcat[128][256] ----------------
// cols 0..127 = W0 ;  cols 128+h*32+k = W1[h][d][k]
__global__ void k_build_wcat(const float* __restrict__ W0, const float* __restrict__ W1,
                             float* __restrict__ Wcat) {
    int idx = blockIdx.x * 256 + threadIdx.x;   // 0..32767
    int d = idx >> 8;
    int j = idx & 255;
    float v;
    if (j < 128) {
        v = W0[d * 128 + j];
    } else {
        int f = j - 128;
        int h = f >> 5;
        int k = f & 31;
        v = W1[h * (DIN * DH) + d * DH + k];
    }
    Wcat[d * 256 + j] = v;
}

// ---------------- K2: GEMM  comb[N][256] = vecs[N][128] @ Wcat[128][256] ----------------
// epilogue: cols<128 get +b0 and relu (self path, pre-norm); cols>=128 raw (vw)
__global__ __launch_bounds__(256)
void k_gemm(const float* __restrict__ A, const float* __restrict__ B,
            const float* __restrict__ b0, float* __restrict__ C) {
    __shared__ float As[64][68];   // +4 pad: keeps column reads ~2-way (free)
    __shared__ float Bs[64][64];
    int tid = threadIdx.x;
    int tx = tid & 15;
    int ty = tid >> 4;
    int n0 = blockIdx.y * 64;
    int j0 = blockIdx.x * 64;

    float acc[4][4] = {};

    for (int k0 = 0; k0 < 128; k0 += 64) {
        // stage A tile (64 rows x 64 k), float4 per thread x4
        #pragma unroll
        for (int i = 0; i < 4; i++) {
            int fidx = tid + i * 256;        // float4 index 0..1023
            int row = fidx >> 4;
            int c4 = (fidx & 15) << 2;
            int gr = n0 + row;
            float4 v = (gr < N_NODES) ? *(const float4*)&A[(size_t)gr * 128 + k0 + c4]
                                      : make_float4(0.f, 0.f, 0.f, 0.f);
            *(float4*)&As[row][c4] = v;
        }
        // stage B tile (64 k x 64 cols)
        #pragma unroll
        for (int i = 0; i < 4; i++) {
            int fidx = tid + i * 256;
            int row = fidx >> 4;
            int c4 = (fidx & 15) << 2;
            *(float4*)&Bs[row][c4] = *(const float4*)&B[(size_t)(k0 + row) * 256 + j0 + c4];
        }
        __syncthreads();

        int r0 = ty * 4;
        #pragma unroll 8
        for (int k = 0; k < 64; k++) {
            float a0 = As[r0 + 0][k];
            float a1 = As[r0 + 1][k];
            float a2 = As[r0 + 2][k];
            float a3 = As[r0 + 3][k];
            float4 b = *(float4*)&Bs[k][tx * 4];
            acc[0][0] += a0 * b.x; acc[0][1] += a0 * b.y; acc[0][2] += a0 * b.z; acc[0][3] += a0 * b.w;
            acc[1][0] += a1 * b.x; acc[1][1] += a1 * b.y; acc[1][2] += a1 * b.z; acc[1][3] += a1 * b.w;
            acc[2][0] += a2 * b.x; acc[2][1] += a2 * b.y; acc[2][2] += a2 * b.z; acc[2][3] += a2 * b.w;
            acc[3][0] += a3 * b.x; acc[3][1] += a3 * b.y; acc[3][2] += a3 * b.z; acc[3][3] += a3 * b.w;
        }
        __syncthreads();
    }

    bool self_half = (j0 < 128);   // uniform per block
    #pragma unroll
    for (int i = 0; i < 4; i++) {
        int gr = n0 + ty * 4 + i;
        if (gr >= N_NODES) continue;
        int gc = j0 + tx * 4;
        float4 v = make_float4(acc[i][0], acc[i][1], acc[i][2], acc[i][3]);
        if (self_half) {
            v.x = fmaxf(v.x + b0[gc + 0], 0.f);
            v.y = fmaxf(v.y + b0[gc + 1], 0.f);
            v.z = fmaxf(v.z + b0[gc + 2], 0.f);
            v.w = fmaxf(v.w + b0[gc + 3], 0.f);
        }
        *(float4*)&C[(size_t)gr * 256 + gc] = v;
    }
}

// ---------------- K3: per-(node,head) attention logits ----------------
__global__ void k_att(const float* __restrict__ comb, const float* __restrict__ att0,
                      const float* __restrict__ att1, const float* __restrict__ attb0,
                      const float* __restrict__ attb1,
                      float* __restrict__ a_self, float* __restrict__ a_neigh) {
    int idx = blockIdx.x * 256 + threadIdx.x;
    if (idx >= N_NODES * NH) return;
    int n = idx >> 2;
    int h = idx & 3;
    const float* vw = &comb[(size_t)n * 256 + 128 + h * 32];
    const float* w0 = &att0[h * DH];
    const float* w1 = &att1[h * DH];
    float s0 = 0.f, s1 = 0.f;
    #pragma unroll
    for (int k = 0; k < 32; k++) {
        float v = vw[k];
        s0 += v * w0[k];
        s1 += v * w1[k];
    }
    a_self[idx]  = s0 + attb0[h];
    a_neigh[idx] = s1 + attb1[h];
}

// ---------------- CSR build ----------------
__global__ void k_hist(const int* __restrict__ rows, int* __restrict__ cnt) {
    int e = blockIdx.x * 256 + threadIdx.x;
    if (e < N_EDGES) atomicAdd(&cnt[rows[e]], 1);
}

__global__ __launch_bounds__(1024)
void k_scan(const int* __restrict__ cnt, int* __restrict__ offs) {
    __shared__ int sh[1024];
    int tid = threadIdx.x;
    const int CH = (N_NODES + 1023) / 1024;   // 98
    int lo = tid * CH;
    int hi = min(lo + CH, N_NODES);
    int s = 0;
    for (int i = lo; i < hi; i++) s += cnt[i];
    sh[tid] = s;
    __syncthreads();
    for (int d = 1; d < 1024; d <<= 1) {
        int v = (tid >= d) ? sh[tid - d] : 0;
        __syncthreads();
        sh[tid] += v;
        __syncthreads();
    }
    int run = sh[tid] - s;                    // exclusive prefix
    for (int i = lo; i < hi; i++) { offs[i] = run; run += cnt[i]; }
    if (tid == 1023) offs[N_NODES] = sh[1023];
}

__global__ void k_fill(const int* __restrict__ rows, const int* __restrict__ offs,
                       int* __restrict__ cursor, int* __restrict__ eidx) {
    int e = blockIdx.x * 256 + threadIdx.x;
    if (e < N_EDGES) {
        int r = rows[e];
        int p = atomicAdd(&cursor[r], 1);
        eidx[offs[r] + p] = e;
    }
}

// ---------------- K6: per-node gather + both row-norms + add ----------------
// one wave (64 lanes) per node; lane owns features 2*lane, 2*lane+1
__global__ __launch_bounds__(256)
void k_final(const float* __restrict__ comb, const float* __restrict__ a_self,
             const float* __restrict__ a_neigh, const float* __restrict__ adj_vals,
             const int* __restrict__ cols, const int* __restrict__ offs,
             const int* __restrict__ eidx, const float* __restrict__ b1,
             const float* __restrict__ off0, const float* __restrict__ sc0,
             const float* __restrict__ off1, const float* __restrict__ sc1,
             float* __restrict__ out) {
    int wave = threadIdx.x >> 6;
    int lane = threadIdx.x & 63;
    int n = blockIdx.x * 4 + wave;
    if (n >= N_NODES) return;
    int h = lane >> 4;              // feature pair lives in head h
    int f0 = lane * 2;
    int f1 = f0 + 1;

    float as_ = a_self[n * 4 + h];
    int lo = offs[n], hi = offs[n + 1];
    float acc0 = 0.f, acc1 = 0.f;
    for (int i = lo; i < hi; i++) {
        int e = eidx[i];
        int c = cols[e];
        float alpha = fmaxf(a_neigh[c * 4 + h] + as_, 0.f) * adj_vals[e];
        float2 v = *(const float2*)&comb[(size_t)c * 256 + 128 + f0];
        acc0 += alpha * v.x;
        acc1 += alpha * v.y;
    }

    // ret_neigh = relu(agg) + b1  (bias outside relu)
    float x0 = fmaxf(acc0, 0.f) + b1[f0];
    float x1 = fmaxf(acc1, 0.f) + b1[f1];

    // row-norm (neighbor path)
    float s = x0 + x1;
    #pragma unroll
    for (int d = 32; d > 0; d >>= 1) s += __shfl_xor(s, d, 64);
    float mean = s * (1.f / 128.f);
    float d0 = x0 - mean, d1 = x1 - mean;
    float q = d0 * d0 + d1 * d1;
    #pragma unroll
    for (int d = 32; d > 0; d >>= 1) q += __shfl_xor(q, d, 64);
    float rinv = rsqrtf(q * (1.f / 128.f) + EPS);
    float y0 = sc1[f0] * d0 * rinv + off1[f0];
    float y1 = sc1[f1] * d1 * rinv + off1[f1];

    // self path: comb cols 0..127 already relu(vecs@W0+b0)
    float u0 = comb[(size_t)n * 256 + f0];
    float u1 = comb[(size_t)n * 256 + f1];
    float s2 = u0 + u1;
    #pragma unroll
    for (int d = 32; d > 0; d >>= 1) s2 += __shfl_xor(s2, d, 64);
    float m2 = s2 * (1.f / 128.f);
    float e0 = u0 - m2, e1 = u1 - m2;
    float q2 = e0 * e0 + e1 * e1;
    #pragma unroll
    for (int d = 32; d > 0; d >>= 1) q2 += __shfl_xor(q2, d, 64);
    float rinv2 = rsqrtf(q2 * (1.f / 128.f) + EPS);
    float z0 = sc0[f0] * e0 * rinv2 + off0[f0];
    float z1 = sc0[f1] * e1 * rinv2 + off0[f1];

    *(float2*)&out[(size_t)n * 128 + f0] = make_float2(y0 + z0, y1 + z1);
}

extern "C" void kernel_launch(void* const* d_in, const int* in_sizes, int n_in,
                              void* d_out, int out_size, void* d_ws, size_t ws_size,
                              hipStream_t stream) {
    const float* vecs     = (const float*)d_in[0];
    const float* adj_vals = (const float*)d_in[1];
    const float* W0       = (const float*)d_in[2];
    const float* b0       = (const float*)d_in[3];
    const float* W1       = (const float*)d_in[4];
    const float* b1       = (const float*)d_in[5];
    const float* att0     = (const float*)d_in[6];
    const float* att1     = (const float*)d_in[7];
    const float* att_b0   = (const float*)d_in[8];
    const float* att_b1   = (const float*)d_in[9];
    const float* off0     = (const float*)d_in[10];
    const float* sc0      = (const float*)d_in[11];
    const float* off1     = (const float*)d_in[12];
    const float* sc1      = (const float*)d_in[13];
    const int*   adj_rows = (const int*)d_in[14];
    const int*   adj_cols = (const int*)d_in[15];
    float* out = (float*)d_out;

    char* ws = (char*)d_ws;
    size_t o = 0;
    auto alloc = [&](size_t bytes) {
        char* p = ws + o;
        o += (bytes + 255) & ~(size_t)255;
        return p;
    };
    float* Wcat    = (float*)alloc((size_t)128 * 256 * 4);
    float* comb    = (float*)alloc((size_t)N_NODES * 256 * 4);   // [N][256]: self|vw
    float* a_self  = (float*)alloc((size_t)N_NODES * NH * 4);
    float* a_neigh = (float*)alloc((size_t)N_NODES * NH * 4);
    int*   cnt     = (int*)alloc((size_t)N_NODES * 4);           // also reused as cursor
    int*   offs    = (int*)alloc((size_t)(N_NODES + 1) * 4);
    int*   eidx    = (int*)alloc((size_t)N_EDGES * 4);

    k_build_wcat<<<128, 256, 0, stream>>>(W0, W1, Wcat);

    dim3 g2(4, (N_NODES + 63) / 64);
    k_gemm<<<g2, 256, 0, stream>>>(vecs, Wcat, b0, comb);

    k_att<<<(N_NODES * NH + 255) / 256, 256, 0, stream>>>(comb, att0, att1, att_b0, att_b1,
                                                          a_self, a_neigh);

    hipMemsetAsync(cnt, 0, (size_t)N_NODES * 4, stream);
    k_hist<<<(N_EDGES + 255) / 256, 256, 0, stream>>>(adj_rows, cnt);
    k_scan<<<1, 1024, 0, stream>>>(cnt, offs);
    hipMemsetAsync(cnt, 0, (size_t)N_NODES * 4, stream);
    k_fill<<<(N_EDGES + 255) / 256, 256, 0, stream>>>(adj_rows, offs, cnt, eidx);

    k_final<<<(N_NODES + 3) / 4, 256, 0, stream>>>(comb, a_self, a_neigh, adj_vals, adj_cols,
                                                   offs, eidx, b1, off0, sc0, off1, sc1, out);
}

// Round 5
// 636.537 us; speedup vs baseline: 1.3162x; 1.3162x over previous
//
#include <hip/hip_runtime.h>

#define N_NODES 100000
#define N_EDGES 1600000
#define DIN 128
#define DOUT 128
#define NH 4
#define DH 32
#define EPS 1e-9f

typedef short bf16x8 __attribute__((ext_vector_type(8)));
typedef float f32x4 __attribute__((ext_vector_type(4)));

__device__ inline unsigned short f2bf(float x) {
    unsigned u = __float_as_uint(x);
    unsigned r = (u + 0x7fffu + ((u >> 16) & 1u)) >> 16;
    return (unsigned short)r;
}
__device__ inline float bflo(unsigned v) { return __uint_as_float(v << 16); }
__device__ inline float bfhi(unsigned v) { return __uint_as_float(v & 0xffff0000u); }

// ---------------- K0: cast vecs f32 -> bf16 ----------------
__global__ void k_cast(const float* __restrict__ in, unsigned short* __restrict__ out) {
    int t = blockIdx.x * 256 + threadIdx.x;        // 8 floats per thread
    const float4* p = (const float4*)(in + (size_t)t * 8);
    float4 a = p[0], b = p[1];
    unsigned short o[8] = {f2bf(a.x), f2bf(a.y), f2bf(a.z), f2bf(a.w),
                           f2bf(b.x), f2bf(b.y), f2bf(b.z), f2bf(b.w)};
    *(bf16x8*)(out + (size_t)t * 8) = *(bf16x8*)o;
}

// ---------------- K1: build W^T bf16 [256][128]: row j = output col ----------------
__global__ void k_build_wtb(const float* __restrict__ W0, const float* __restrict__ W1,
                            unsigned short* __restrict__ Wtb) {
    int idx = blockIdx.x * 256 + threadIdx.x;      // 0..32767
    int j = idx >> 7;                              // output col 0..255
    int k = idx & 127;                             // input dim
    float v;
    if (j < 128) v = W0[k * 128 + j];
    else {
        int f = j - 128;
        v = W1[(f >> 5) * (DIN * DH) + k * DH + (f & 31)];
    }
    Wtb[j * 128 + k] = f2bf(v);
}

// ---------------- K2: MFMA GEMM  [M x 256] = vecsb[M x 128] @ W ----------------
// tile: 64 rows x 128 cols per block (grid.x=2 col-halves), 4 waves, K=128 single stage
// cols<128 -> comb_self (relu(x+b0), f32). cols>=128 -> vwb (bf16)
__global__ __launch_bounds__(256)
void k_gemm(const unsigned short* __restrict__ A, const unsigned short* __restrict__ B,
            const float* __restrict__ b0, float* __restrict__ comb_self,
            unsigned short* __restrict__ vwb) {
    __shared__ short As[64][136];    // +8 bf16 pad: 16B-aligned rows, ~2-way banks
    __shared__ short Bs[128][136];
    int tid = threadIdx.x;
    int wave = tid >> 6;
    int lane = tid & 63;
    int m0 = blockIdx.y * 64;
    int j0 = blockIdx.x * 128;

    // stage A: 64x128 bf16 = 1024 x 16B chunks (4 iters x 256 threads)
    #pragma unroll
    for (int it = 0; it < 4; it++) {
        int ch = tid + it * 256;
        int row = ch >> 4, k8 = (ch & 15) << 3;
        *(bf16x8*)&As[row][k8] = *(const bf16x8*)&A[(size_t)(m0 + row) * 128 + k8];
    }
    // stage B^T: 128x128 bf16 = 2048 x 16B chunks (8 iters x 256 threads)
    // BUG FIX (r4): was 4 iters -> Bs rows 64..127 uninitialized -> NaN
    #pragma unroll
    for (int it = 0; it < 8; it++) {
        int ch = tid + it * 256;
        int j = ch >> 4, k8 = (ch & 15) << 3;
        *(bf16x8*)&Bs[j][k8] = *(const bf16x8*)&B[(size_t)(j0 + j) * 128 + k8];
    }
    __syncthreads();

    int lrow = lane & 15;
    int g8 = (lane >> 4) << 3;
    f32x4 acc[4][2] = {};
    #pragma unroll
    for (int kk = 0; kk < 4; kk++) {
        int kb = kk * 32 + g8;
        bf16x8 a[4], b[2];
        #pragma unroll
        for (int r = 0; r < 4; r++) a[r] = *(bf16x8*)&As[r * 16 + lrow][kb];
        #pragma unroll
        for (int q = 0; q < 2; q++) b[q] = *(bf16x8*)&Bs[wave * 32 + q * 16 + lrow][kb];
        #pragma unroll
        for (int r = 0; r < 4; r++)
            #pragma unroll
            for (int q = 0; q < 2; q++)
                acc[r][q] = __builtin_amdgcn_mfma_f32_16x16x32_bf16(a[r], b[q], acc[r][q], 0, 0, 0);
    }

    // C/D: col = lane&15, row = (lane>>4)*4 + reg
    int rbase = (lane >> 4) << 2;
    #pragma unroll
    for (int r = 0; r < 4; r++) {
        #pragma unroll
        for (int q = 0; q < 2; q++) {
            int gcol = j0 + wave * 32 + q * 16 + lrow;
            #pragma unroll
            for (int reg = 0; reg < 4; reg++) {
                int grow = m0 + r * 16 + rbase + reg;
                if (grow >= N_NODES) continue;
                float v = acc[r][q][reg];
                if (gcol < 128) {
                    comb_self[(size_t)grow * 128 + gcol] = fmaxf(v + b0[gcol], 0.f);
                } else {
                    vwb[(size_t)grow * 128 + (gcol - 128)] = f2bf(v);
                }
            }
        }
    }
}

// ---------------- K3: per-(node,head) attention logits from bf16 vw ----------------
__global__ void k_att(const unsigned short* __restrict__ vwb, const float* __restrict__ att0,
                      const float* __restrict__ att1, const float* __restrict__ attb0,
                      const float* __restrict__ attb1,
                      float* __restrict__ a_self, float* __restrict__ a_neigh) {
    int idx = blockIdx.x * 256 + threadIdx.x;
    if (idx >= N_NODES * NH) return;
    int n = idx >> 2;
    int h = idx & 3;
    const unsigned* vw = (const unsigned*)&vwb[(size_t)n * 128 + h * 32];
    const float* w0 = &att0[h * DH];
    const float* w1 = &att1[h * DH];
    float s0 = 0.f, s1 = 0.f;
    #pragma unroll
    for (int k = 0; k < 16; k++) {
        unsigned v = vw[k];
        float v0 = bflo(v), v1 = bfhi(v);
        s0 += v0 * w0[2 * k] + v1 * w0[2 * k + 1];
        s1 += v0 * w1[2 * k] + v1 * w1[2 * k + 1];
    }
    a_self[idx]  = s0 + attb0[h];
    a_neigh[idx] = s1 + attb1[h];
}

// ---------------- CSR build ----------------
__global__ void k_hist(const int* __restrict__ rows, int* __restrict__ cnt) {
    int e = blockIdx.x * 256 + threadIdx.x;
    if (e < N_EDGES) atomicAdd(&cnt[rows[e]], 1);
}

__global__ __launch_bounds__(1024)
void k_scan(const int* __restrict__ cnt, int* __restrict__ offs) {
    __shared__ int sh[1024];
    int tid = threadIdx.x;
    const int CH = (N_NODES + 1023) / 1024;
    int lo = tid * CH;
    int hi = min(lo + CH, N_NODES);
    int s = 0;
    for (int i = lo; i < hi; i++) s += cnt[i];
    sh[tid] = s;
    __syncthreads();
    for (int d = 1; d < 1024; d <<= 1) {
        int v = (tid >= d) ? sh[tid - d] : 0;
        __syncthreads();
        sh[tid] += v;
        __syncthreads();
    }
    int run = sh[tid] - s;
    for (int i = lo; i < hi; i++) { offs[i] = run; run += cnt[i]; }
    if (tid == 1023) offs[N_NODES] = sh[1023];
}

// K5: fill CSR slots AND precompute per-edge per-head alpha (removes all random
// metadata loads from k_final's serial chain)
__global__ void k_fill(const int* __restrict__ rows, const int* __restrict__ cols,
                       const float* __restrict__ adj_vals,
                       const float* __restrict__ a_self, const float* __restrict__ a_neigh,
                       const int* __restrict__ offs, int* __restrict__ cursor,
                       int* __restrict__ ccsr, float* __restrict__ alphaE) {
    int e = blockIdx.x * 256 + threadIdx.x;
    if (e >= N_EDGES) return;
    int r = rows[e];
    int c = cols[e];
    int p = atomicAdd(&cursor[r], 1);
    int slot = offs[r] + p;
    ccsr[slot] = c;
    float av = adj_vals[e];
    float4 an = *(const float4*)&a_neigh[c * 4];
    float4 as = *(const float4*)&a_self[r * 4];
    float4 al;
    al.x = fmaxf(an.x + as.x, 0.f) * av;
    al.y = fmaxf(an.y + as.y, 0.f) * av;
    al.z = fmaxf(an.z + as.z, 0.f) * av;
    al.w = fmaxf(an.w + as.w, 0.f) * av;
    *(float4*)&alphaE[(size_t)slot * 4] = al;
}

// ---------------- K6: per-node gather + both row-norms + add ----------------
// one wave per node; lane owns features 2*lane, 2*lane+1 (head h = lane>>4)
__global__ __launch_bounds__(256)
void k_final(const float* __restrict__ comb_self, const unsigned short* __restrict__ vwb,
             const float* __restrict__ alphaE, const int* __restrict__ ccsr,
             const int* __restrict__ offs, const float* __restrict__ b1,
             const float* __restrict__ off0, const float* __restrict__ sc0,
             const float* __restrict__ off1, const float* __restrict__ sc1,
             float* __restrict__ out) {
    int wave = threadIdx.x >> 6;
    int lane = threadIdx.x & 63;
    int n = blockIdx.x * 4 + wave;
    if (n >= N_NODES) return;
    int h = lane >> 4;
    int f0 = lane * 2;
    int f1 = f0 + 1;

    int lo = offs[n], hi = offs[n + 1];
    float acc0 = 0.f, acc1 = 0.f;

#define BODY(I) { \
        int c_ = ccsr[(I)]; \
        float al_ = alphaE[(size_t)(I) * 4 + h]; \
        unsigned v_ = *(const unsigned*)&vwb[(size_t)c_ * 128 + f0]; \
        acc0 += al_ * bflo(v_); \
        acc1 += al_ * bfhi(v_); }

    int i = lo;
    for (; i + 4 <= hi; i += 4) { BODY(i) BODY(i + 1) BODY(i + 2) BODY(i + 3) }
    for (; i < hi; i++) BODY(i)
#undef BODY

    // ret_neigh = relu(agg) + b1 (bias outside relu), then row-norm
    float x0 = fmaxf(acc0, 0.f) + b1[f0];
    float x1 = fmaxf(acc1, 0.f) + b1[f1];
    float s = x0 + x1;
    #pragma unroll
    for (int d = 32; d > 0; d >>= 1) s += __shfl_xor(s, d, 64);
    float mean = s * (1.f / 128.f);
    float d0 = x0 - mean, d1 = x1 - mean;
    float q = d0 * d0 + d1 * d1;
    #pragma unroll
    for (int d = 32; d > 0; d >>= 1) q += __shfl_xor(q, d, 64);
    float rinv = rsqrtf(q * (1.f / 128.f) + EPS);
    float y0 = sc1[f0] * d0 * rinv + off1[f0];
    float y1 = sc1[f1] * d1 * rinv + off1[f1];

    // self path (already relu(vecs@W0+b0)), row-norm
    float2 u = *(const float2*)&comb_self[(size_t)n * 128 + f0];
    float s2 = u.x + u.y;
    #pragma unroll
    for (int d = 32; d > 0; d >>= 1) s2 += __shfl_xor(s2, d, 64);
    float m2 = s2 * (1.f / 128.f);
    float e0 = u.x - m2, e1 = u.y - m2;
    float q2 = e0 * e0 + e1 * e1;
    #pragma unroll
    for (int d = 32; d > 0; d >>= 1) q2 += __shfl_xor(q2, d, 64);
    float rinv2 = rsqrtf(q2 * (1.f / 128.f) + EPS);
    float z0 = sc0[f0] * e0 * rinv2 + off0[f0];
    float z1 = sc0[f1] * e1 * rinv2 + off0[f1];

    *(float2*)&out[(size_t)n * 128 + f0] = make_float2(y0 + z0, y1 + z1);
}

extern "C" void kernel_launch(void* const* d_in, const int* in_sizes, int n_in,
                              void* d_out, int out_size, void* d_ws, size_t ws_size,
                              hipStream_t stream) {
    const float* vecs     = (const float*)d_in[0];
    const float* adj_vals = (const float*)d_in[1];
    const float* W0       = (const float*)d_in[2];
    const float* b0       = (const float*)d_in[3];
    const float* W1       = (const float*)d_in[4];
    const float* b1       = (const float*)d_in[5];
    const float* att0     = (const float*)d_in[6];
    const float* att1     = (const float*)d_in[7];
    const float* att_b0   = (const float*)d_in[8];
    const float* att_b1   = (const float*)d_in[9];
    const float* off0     = (const float*)d_in[10];
    const float* sc0      = (const float*)d_in[11];
    const float* off1     = (const float*)d_in[12];
    const float* sc1      = (const float*)d_in[13];
    const int*   adj_rows = (const int*)d_in[14];
    const int*   adj_cols = (const int*)d_in[15];
    float* out = (float*)d_out;

    char* ws = (char*)d_ws;
    size_t o = 0;
    auto alloc = [&](size_t bytes) {
        char* p = ws + o;
        o += (bytes + 255) & ~(size_t)255;
        return p;
    };
    const int MPAD = 100032;                                        // 64-aligned M
    // vecsb (25.61 MB) is dead after k_gemm; alphaE (25.6 MB) is born at k_fill.
    // Alias them to keep total ws usage at ~112.9 MB (round-1 proven footprint).
    unsigned short* vecsb = (unsigned short*)alloc((size_t)MPAD * 128 * 2);
    unsigned short* Wtb   = (unsigned short*)alloc((size_t)256 * 128 * 2);
    float* comb_self      = (float*)alloc((size_t)N_NODES * 128 * 4);
    unsigned short* vwb   = (unsigned short*)alloc((size_t)N_NODES * 128 * 2);
    float* a_self         = (float*)alloc((size_t)N_NODES * NH * 4);
    float* a_neigh        = (float*)alloc((size_t)N_NODES * NH * 4);
    int*   cnt            = (int*)alloc((size_t)N_NODES * 4);
    int*   offs           = (int*)alloc((size_t)(N_NODES + 1) * 4);
    int*   ccsr           = (int*)alloc((size_t)N_EDGES * 4);
    float* alphaE         = (float*)vecsb;   // alias: disjoint lifetime, 25.6MB <= 25.61MB

    k_cast<<<(N_NODES * 128 / 8 + 255) / 256, 256, 0, stream>>>(vecs, vecsb);
    k_build_wtb<<<128, 256, 0, stream>>>(W0, W1, Wtb);

    dim3 g2(2, MPAD / 64);
    k_gemm<<<g2, 256, 0, stream>>>(vecsb, Wtb, b0, comb_self, vwb);

    k_att<<<(N_NODES * NH + 255) / 256, 256, 0, stream>>>(vwb, att0, att1, att_b0, att_b1,
                                                          a_self, a_neigh);

    hipMemsetAsync(cnt, 0, (size_t)N_NODES * 4, stream);
    k_hist<<<(N_EDGES + 255) / 256, 256, 0, stream>>>(adj_rows, cnt);
    k_scan<<<1, 1024, 0, stream>>>(cnt, offs);
    hipMemsetAsync(cnt, 0, (size_t)N_NODES * 4, stream);
    k_fill<<<(N_EDGES + 255) / 256, 256, 0, stream>>>(adj_rows, adj_cols, adj_vals,
                                                      a_self, a_neigh, offs, cnt, ccsr, alphaE);

    k_final<<<(N_NODES + 3) / 4, 256, 0, stream>>>(comb_self, vwb, alphaE, ccsr, offs,
                                                   b1, off0, sc0, off1, sc1, out);
}

// Round 6
// 474.605 us; speedup vs baseline: 1.7653x; 1.3412x over previous
//
#include <hip/hip_runtime.h>

#define N_NODES 100000
#define N_EDGES 1600000
#define DIN 128
#define DOUT 128
#define NH 4
#define DH 32
#define EPS 1e-9f
#define NBLK 391   // ceil(N_NODES/256)

typedef short bf16x8 __attribute__((ext_vector_type(8)));
typedef float f32x4 __attribute__((ext_vector_type(4)));

__device__ inline unsigned short f2bf(float x) {
    unsigned u = __float_as_uint(x);
    unsigned r = (u + 0x7fffu + ((u >> 16) & 1u)) >> 16;
    return (unsigned short)r;
}
__device__ inline float bflo(unsigned v) { return __uint_as_float(v << 16); }
__device__ inline float bfhi(unsigned v) { return __uint_as_float(v & 0xffff0000u); }

// ---------------- K0: cast vecs f32 -> bf16 ----------------
__global__ void k_cast(const float* __restrict__ in, unsigned short* __restrict__ out) {
    int t = blockIdx.x * 256 + threadIdx.x;        // 8 floats per thread
    const float4* p = (const float4*)(in + (size_t)t * 8);
    float4 a = p[0], b = p[1];
    unsigned short o[8] = {f2bf(a.x), f2bf(a.y), f2bf(a.z), f2bf(a.w),
                           f2bf(b.x), f2bf(b.y), f2bf(b.z), f2bf(b.w)};
    *(bf16x8*)(out + (size_t)t * 8) = *(bf16x8*)o;
}

// ---------------- K1: build W^T bf16 [256][128]: row j = output col ----------------
__global__ void k_build_wtb(const float* __restrict__ W0, const float* __restrict__ W1,
                            unsigned short* __restrict__ Wtb) {
    int idx = blockIdx.x * 256 + threadIdx.x;      // 0..32767
    int j = idx >> 7;                              // output col 0..255
    int k = idx & 127;                             // input dim
    float v;
    if (j < 128) v = W0[k * 128 + j];
    else {
        int f = j - 128;
        v = W1[(f >> 5) * (DIN * DH) + k * DH + (f & 31)];
    }
    Wtb[j * 128 + k] = f2bf(v);
}

// ---------------- K2: MFMA GEMM  [M x 256] = vecsb[M x 128] @ W ----------------
__global__ __launch_bounds__(256)
void k_gemm(const unsigned short* __restrict__ A, const unsigned short* __restrict__ B,
            const float* __restrict__ b0, float* __restrict__ comb_self,
            unsigned short* __restrict__ vwb) {
    __shared__ short As[64][136];
    __shared__ short Bs[128][136];
    int tid = threadIdx.x;
    int wave = tid >> 6;
    int lane = tid & 63;
    int m0 = blockIdx.y * 64;
    int j0 = blockIdx.x * 128;

    #pragma unroll
    for (int it = 0; it < 4; it++) {
        int ch = tid + it * 256;
        int row = ch >> 4, k8 = (ch & 15) << 3;
        *(bf16x8*)&As[row][k8] = *(const bf16x8*)&A[(size_t)(m0 + row) * 128 + k8];
    }
    #pragma unroll
    for (int it = 0; it < 8; it++) {
        int ch = tid + it * 256;
        int j = ch >> 4, k8 = (ch & 15) << 3;
        *(bf16x8*)&Bs[j][k8] = *(const bf16x8*)&B[(size_t)(j0 + j) * 128 + k8];
    }
    __syncthreads();

    int lrow = lane & 15;
    int g8 = (lane >> 4) << 3;
    f32x4 acc[4][2] = {};
    #pragma unroll
    for (int kk = 0; kk < 4; kk++) {
        int kb = kk * 32 + g8;
        bf16x8 a[4], b[2];
        #pragma unroll
        for (int r = 0; r < 4; r++) a[r] = *(bf16x8*)&As[r * 16 + lrow][kb];
        #pragma unroll
        for (int q = 0; q < 2; q++) b[q] = *(bf16x8*)&Bs[wave * 32 + q * 16 + lrow][kb];
        #pragma unroll
        for (int r = 0; r < 4; r++)
            #pragma unroll
            for (int q = 0; q < 2; q++)
                acc[r][q] = __builtin_amdgcn_mfma_f32_16x16x32_bf16(a[r], b[q], acc[r][q], 0, 0, 0);
    }

    int rbase = (lane >> 4) << 2;
    #pragma unroll
    for (int r = 0; r < 4; r++) {
        #pragma unroll
        for (int q = 0; q < 2; q++) {
            int gcol = j0 + wave * 32 + q * 16 + lrow;
            #pragma unroll
            for (int reg = 0; reg < 4; reg++) {
                int grow = m0 + r * 16 + rbase + reg;
                if (grow >= N_NODES) continue;
                float v = acc[r][q][reg];
                if (gcol < 128) {
                    comb_self[(size_t)grow * 128 + gcol] = fmaxf(v + b0[gcol], 0.f);
                } else {
                    vwb[(size_t)grow * 128 + (gcol - 128)] = f2bf(v);
                }
            }
        }
    }
}

// ---------------- K3: per-(node,head) attention logits ----------------
__global__ void k_att(const unsigned short* __restrict__ vwb, const float* __restrict__ att0,
                      const float* __restrict__ att1, const float* __restrict__ attb0,
                      const float* __restrict__ attb1,
                      float* __restrict__ a_self, float* __restrict__ a_neigh) {
    int idx = blockIdx.x * 256 + threadIdx.x;
    if (idx >= N_NODES * NH) return;
    int n = idx >> 2;
    int h = idx & 3;
    const unsigned* vw = (const unsigned*)&vwb[(size_t)n * 128 + h * 32];
    const float* w0 = &att0[h * DH];
    const float* w1 = &att1[h * DH];
    float s0 = 0.f, s1 = 0.f;
    #pragma unroll
    for (int k = 0; k < 16; k++) {
        unsigned v = vw[k];
        float v0 = bflo(v), v1 = bfhi(v);
        s0 += v0 * w0[2 * k] + v1 * w0[2 * k + 1];
        s1 += v0 * w1[2 * k] + v1 * w1[2 * k + 1];
    }
    a_self[idx]  = s0 + attb0[h];
    a_neigh[idx] = s1 + attb1[h];
}

// ---------------- CSR build ----------------
__global__ void k_hist(const int* __restrict__ rows, int* __restrict__ cnt) {
    int e = blockIdx.x * 256 + threadIdx.x;
    if (e < N_EDGES) atomicAdd(&cnt[rows[e]], 1);
}

// scan stage A: per-block sum of 256 cnt entries
__global__ __launch_bounds__(256)
void k_scanA(const int* __restrict__ cnt, int* __restrict__ bsum) {
    int t = threadIdx.x;
    int idx = blockIdx.x * 256 + t;
    int v = (idx < N_NODES) ? cnt[idx] : 0;
    #pragma unroll
    for (int d = 1; d < 64; d <<= 1) v += __shfl_xor(v, d, 64);
    __shared__ int ws[4];
    if ((t & 63) == 0) ws[t >> 6] = v;
    __syncthreads();
    if (t == 0) bsum[blockIdx.x] = ws[0] + ws[1] + ws[2] + ws[3];
}

// scan stage B: single block scans the 391 block sums -> exclusive bases
__global__ __launch_bounds__(512)
void k_scanB(const int* __restrict__ bsum, int* __restrict__ bbase, int* __restrict__ offs) {
    __shared__ int sh[512];
    int t = threadIdx.x;
    int v = (t < NBLK) ? bsum[t] : 0;
    sh[t] = v;
    __syncthreads();
    for (int d = 1; d < 512; d <<= 1) {
        int x = (t >= d) ? sh[t - d] : 0;
        __syncthreads();
        sh[t] += x;
        __syncthreads();
    }
    if (t < NBLK) bbase[t] = sh[t] - v;     // exclusive base
    if (t == 0) offs[N_NODES] = N_EDGES;
}

// scan stage C: per-block exclusive scan + base -> offs
__global__ __launch_bounds__(256)
void k_scanC(const int* __restrict__ cnt, const int* __restrict__ bbase,
             int* __restrict__ offs) {
    int t = threadIdx.x;
    int lane = t & 63;
    int w = t >> 6;
    int idx = blockIdx.x * 256 + t;
    int v = (idx < N_NODES) ? cnt[idx] : 0;
    int incl = v;
    #pragma unroll
    for (int d = 1; d < 64; d <<= 1) {
        int x = __shfl_up(incl, d, 64);
        if (lane >= d) incl += x;
    }
    __shared__ int wsum[4];
    if (lane == 63) wsum[w] = incl;
    __syncthreads();
    int wbase = 0;
    #pragma unroll
    for (int i = 0; i < 4; i++) if (i < w) wbase += wsum[i];
    if (idx < N_NODES) offs[idx] = incl - v + wbase + bbase[blockIdx.x];
}

// K5: fill CSR slots + per-edge per-head alpha. cursor pre-initialized to offs
// (D2D copy), so atomicAdd yields the absolute slot directly.
__global__ void k_fill(const int* __restrict__ rows, const int* __restrict__ cols,
                       const float* __restrict__ adj_vals,
                       const float* __restrict__ a_self, const float* __restrict__ a_neigh,
                       int* __restrict__ cursor,
                       int* __restrict__ ccsr, float* __restrict__ alphaE) {
    int e = blockIdx.x * 256 + threadIdx.x;
    if (e >= N_EDGES) return;
    int r = rows[e];
    int c = cols[e];
    int slot = atomicAdd(&cursor[r], 1);
    ccsr[slot] = c;
    float av = adj_vals[e];
    float4 an = *(const float4*)&a_neigh[c * 4];
    float4 as = *(const float4*)&a_self[r * 4];
    float4 al;
    al.x = fmaxf(an.x + as.x, 0.f) * av;
    al.y = fmaxf(an.y + as.y, 0.f) * av;
    al.z = fmaxf(an.z + as.z, 0.f) * av;
    al.w = fmaxf(an.w + as.w, 0.f) * av;
    *(float4*)&alphaE[(size_t)slot * 4] = al;
}

// ---------------- K6: per-node gather + both row-norms + add ----------------
__global__ __launch_bounds__(256)
void k_final(const float* __restrict__ comb_self, const unsigned short* __restrict__ vwb,
             const float* __restrict__ alphaE, const int* __restrict__ ccsr,
             const int* __restrict__ offs, const float* __restrict__ b1,
             const float* __restrict__ off0, const float* __restrict__ sc0,
             const float* __restrict__ off1, const float* __restrict__ sc1,
             float* __restrict__ out) {
    int wave = threadIdx.x >> 6;
    int lane = threadIdx.x & 63;
    int n = blockIdx.x * 4 + wave;
    if (n >= N_NODES) return;
    int h = lane >> 4;
    int f0 = lane * 2;
    int f1 = f0 + 1;

    int lo = offs[n], hi = offs[n + 1];
    float acc0 = 0.f, acc1 = 0.f;

#define BODY(I) { \
        int c_ = ccsr[(I)]; \
        float al_ = alphaE[(size_t)(I) * 4 + h]; \
        unsigned v_ = *(const unsigned*)&vwb[(size_t)c_ * 128 + f0]; \
        acc0 += al_ * bflo(v_); \
        acc1 += al_ * bfhi(v_); }

    int i = lo;
    for (; i + 4 <= hi; i += 4) { BODY(i) BODY(i + 1) BODY(i + 2) BODY(i + 3) }
    for (; i < hi; i++) BODY(i)
#undef BODY

    float x0 = fmaxf(acc0, 0.f) + b1[f0];
    float x1 = fmaxf(acc1, 0.f) + b1[f1];
    float s = x0 + x1;
    #pragma unroll
    for (int d = 32; d > 0; d >>= 1) s += __shfl_xor(s, d, 64);
    float mean = s * (1.f / 128.f);
    float d0 = x0 - mean, d1 = x1 - mean;
    float q = d0 * d0 + d1 * d1;
    #pragma unroll
    for (int d = 32; d > 0; d >>= 1) q += __shfl_xor(q, d, 64);
    float rinv = rsqrtf(q * (1.f / 128.f) + EPS);
    float y0 = sc1[f0] * d0 * rinv + off1[f0];
    float y1 = sc1[f1] * d1 * rinv + off1[f1];

    float2 u = *(const float2*)&comb_self[(size_t)n * 128 + f0];
    float s2 = u.x + u.y;
    #pragma unroll
    for (int d = 32; d > 0; d >>= 1) s2 += __shfl_xor(s2, d, 64);
    float m2 = s2 * (1.f / 128.f);
    float e0 = u.x - m2, e1 = u.y - m2;
    float q2 = e0 * e0 + e1 * e1;
    #pragma unroll
    for (int d = 32; d > 0; d >>= 1) q2 += __shfl_xor(q2, d, 64);
    float rinv2 = rsqrtf(q2 * (1.f / 128.f) + EPS);
    float z0 = sc0[f0] * e0 * rinv2 + off0[f0];
    float z1 = sc0[f1] * e1 * rinv2 + off0[f1];

    *(float2*)&out[(size_t)n * 128 + f0] = make_float2(y0 + z0, y1 + z1);
}

extern "C" void kernel_launch(void* const* d_in, const int* in_sizes, int n_in,
                              void* d_out, int out_size, void* d_ws, size_t ws_size,
                              hipStream_t stream) {
    const float* vecs     = (const float*)d_in[0];
    const float* adj_vals = (const float*)d_in[1];
    const float* W0       = (const float*)d_in[2];
    const float* b0       = (const float*)d_in[3];
    const float* W1       = (const float*)d_in[4];
    const float* b1       = (const float*)d_in[5];
    const float* att0     = (const float*)d_in[6];
    const float* att1     = (const float*)d_in[7];
    const float* att_b0   = (const float*)d_in[8];
    const float* att_b1   = (const float*)d_in[9];
    const float* off0     = (const float*)d_in[10];
    const float* sc0      = (const float*)d_in[11];
    const float* off1     = (const float*)d_in[12];
    const float* sc1      = (const float*)d_in[13];
    const int*   adj_rows = (const int*)d_in[14];
    const int*   adj_cols = (const int*)d_in[15];
    float* out = (float*)d_out;

    char* ws = (char*)d_ws;
    size_t o = 0;
    auto alloc = [&](size_t bytes) {
        char* p = ws + o;
        o += (bytes + 255) & ~(size_t)255;
        return p;
    };
    const int MPAD = 100032;                                        // 64-aligned M
    // vecsb (25.61 MB) dead after k_gemm; alphaE (25.6 MB) born at k_fill -> alias.
    unsigned short* vecsb = (unsigned short*)alloc((size_t)MPAD * 128 * 2);
    unsigned short* Wtb   = (unsigned short*)alloc((size_t)256 * 128 * 2);
    float* comb_self      = (float*)alloc((size_t)N_NODES * 128 * 4);
    unsigned short* vwb   = (unsigned short*)alloc((size_t)N_NODES * 128 * 2);
    float* a_self         = (float*)alloc((size_t)N_NODES * NH * 4);
    float* a_neigh        = (float*)alloc((size_t)N_NODES * NH * 4);
    int*   cnt            = (int*)alloc((size_t)N_NODES * 4);       // hist; later cursor
    int*   offs           = (int*)alloc((size_t)(N_NODES + 1) * 4);
    int*   ccsr           = (int*)alloc((size_t)N_EDGES * 4);
    int*   bsum           = (int*)alloc((size_t)NBLK * 4);
    int*   bbase          = (int*)alloc((size_t)NBLK * 4);
    float* alphaE         = (float*)vecsb;   // alias: disjoint lifetime

    k_cast<<<(N_NODES * 128 / 8 + 255) / 256, 256, 0, stream>>>(vecs, vecsb);
    k_build_wtb<<<128, 256, 0, stream>>>(W0, W1, Wtb);

    dim3 g2(2, MPAD / 64);
    k_gemm<<<g2, 256, 0, stream>>>(vecsb, Wtb, b0, comb_self, vwb);

    k_att<<<(N_NODES * NH + 255) / 256, 256, 0, stream>>>(vwb, att0, att1, att_b0, att_b1,
                                                          a_self, a_neigh);

    hipMemsetAsync(cnt, 0, (size_t)N_NODES * 4, stream);
    k_hist<<<(N_EDGES + 255) / 256, 256, 0, stream>>>(adj_rows, cnt);
    k_scanA<<<NBLK, 256, 0, stream>>>(cnt, bsum);
    k_scanB<<<1, 512, 0, stream>>>(bsum, bbase, offs);
    k_scanC<<<NBLK, 256, 0, stream>>>(cnt, bbase, offs);
    // cursor := offs (cnt buffer is dead after scanC; reuse it as cursor)
    hipMemcpyAsync(cnt, offs, (size_t)N_NODES * 4, hipMemcpyDeviceToDevice, stream);
    k_fill<<<(N_EDGES + 255) / 256, 256, 0, stream>>>(adj_rows, adj_cols, adj_vals,
                                                      a_self, a_neigh, cnt, ccsr, alphaE);

    k_final<<<(N_NODES + 3) / 4, 256, 0, stream>>>(comb_self, vwb, alphaE, ccsr, offs,
                                                   b1, off0, sc0, off1, sc1, out);
}

// Round 7
// 468.237 us; speedup vs baseline: 1.7893x; 1.0136x over previous
//
#include <hip/hip_runtime.h>

#define N_NODES 100000
#define N_EDGES 1600000
#define DIN 128
#define DOUT 128
#define NH 4
#define DH 32
#define EPS 1e-9f
#define NBLK 391   // ceil(N_NODES/256)

typedef short bf16x8 __attribute__((ext_vector_type(8)));
typedef float f32x4 __attribute__((ext_vector_type(4)));

__device__ inline unsigned short f2bf(float x) {
    unsigned u = __float_as_uint(x);
    unsigned r = (u + 0x7fffu + ((u >> 16) & 1u)) >> 16;
    return (unsigned short)r;
}
__device__ inline float bflo(unsigned v) { return __uint_as_float(v << 16); }
__device__ inline float bfhi(unsigned v) { return __uint_as_float(v & 0xffff0000u); }

// ---------------- K0: cast vecs f32 -> bf16 ----------------
__global__ void k_cast(const float* __restrict__ in, unsigned short* __restrict__ out) {
    int t = blockIdx.x * 256 + threadIdx.x;        // 8 floats per thread
    const float4* p = (const float4*)(in + (size_t)t * 8);
    float4 a = p[0], b = p[1];
    unsigned short o[8] = {f2bf(a.x), f2bf(a.y), f2bf(a.z), f2bf(a.w),
                           f2bf(b.x), f2bf(b.y), f2bf(b.z), f2bf(b.w)};
    *(bf16x8*)(out + (size_t)t * 8) = *(bf16x8*)o;
}

// ---------------- K1: build W^T bf16 [256][128]: row j = output col ----------------
__global__ void k_build_wtb(const float* __restrict__ W0, const float* __restrict__ W1,
                            unsigned short* __restrict__ Wtb) {
    int idx = blockIdx.x * 256 + threadIdx.x;      // 0..32767
    int j = idx >> 7;                              // output col 0..255
    int k = idx & 127;                             // input dim
    float v;
    if (j < 128) v = W0[k * 128 + j];
    else {
        int f = j - 128;
        v = W1[(f >> 5) * (DIN * DH) + k * DH + (f & 31)];
    }
    Wtb[j * 128 + k] = f2bf(v);
}

// ---------------- K2: MFMA GEMM  [M x 256] = vecsb[M x 128] @ W ----------------
__global__ __launch_bounds__(256)
void k_gemm(const unsigned short* __restrict__ A, const unsigned short* __restrict__ B,
            const float* __restrict__ b0, float* __restrict__ comb_self,
            unsigned short* __restrict__ vwb) {
    __shared__ short As[64][136];
    __shared__ short Bs[128][136];
    int tid = threadIdx.x;
    int wave = tid >> 6;
    int lane = tid & 63;
    int m0 = blockIdx.y * 64;
    int j0 = blockIdx.x * 128;

    #pragma unroll
    for (int it = 0; it < 4; it++) {
        int ch = tid + it * 256;
        int row = ch >> 4, k8 = (ch & 15) << 3;
        *(bf16x8*)&As[row][k8] = *(const bf16x8*)&A[(size_t)(m0 + row) * 128 + k8];
    }
    #pragma unroll
    for (int it = 0; it < 8; it++) {
        int ch = tid + it * 256;
        int j = ch >> 4, k8 = (ch & 15) << 3;
        *(bf16x8*)&Bs[j][k8] = *(const bf16x8*)&B[(size_t)(j0 + j) * 128 + k8];
    }
    __syncthreads();

    int lrow = lane & 15;
    int g8 = (lane >> 4) << 3;
    f32x4 acc[4][2] = {};
    #pragma unroll
    for (int kk = 0; kk < 4; kk++) {
        int kb = kk * 32 + g8;
        bf16x8 a[4], b[2];
        #pragma unroll
        for (int r = 0; r < 4; r++) a[r] = *(bf16x8*)&As[r * 16 + lrow][kb];
        #pragma unroll
        for (int q = 0; q < 2; q++) b[q] = *(bf16x8*)&Bs[wave * 32 + q * 16 + lrow][kb];
        #pragma unroll
        for (int r = 0; r < 4; r++)
            #pragma unroll
            for (int q = 0; q < 2; q++)
                acc[r][q] = __builtin_amdgcn_mfma_f32_16x16x32_bf16(a[r], b[q], acc[r][q], 0, 0, 0);
    }

    int rbase = (lane >> 4) << 2;
    #pragma unroll
    for (int r = 0; r < 4; r++) {
        #pragma unroll
        for (int q = 0; q < 2; q++) {
            int gcol = j0 + wave * 32 + q * 16 + lrow;
            #pragma unroll
            for (int reg = 0; reg < 4; reg++) {
                int grow = m0 + r * 16 + rbase + reg;
                if (grow >= N_NODES) continue;
                float v = acc[r][q][reg];
                if (gcol < 128) {
                    comb_self[(size_t)grow * 128 + gcol] = fmaxf(v + b0[gcol], 0.f);
                } else {
                    vwb[(size_t)grow * 128 + (gcol - 128)] = f2bf(v);
                }
            }
        }
    }
}

// ---------------- K3: per-(node,head) attention logits ----------------
__global__ void k_att(const unsigned short* __restrict__ vwb, const float* __restrict__ att0,
                      const float* __restrict__ att1, const float* __restrict__ attb0,
                      const float* __restrict__ attb1,
                      float* __restrict__ a_self, float* __restrict__ a_neigh) {
    int idx = blockIdx.x * 256 + threadIdx.x;
    if (idx >= N_NODES * NH) return;
    int n = idx >> 2;
    int h = idx & 3;
    const unsigned* vw = (const unsigned*)&vwb[(size_t)n * 128 + h * 32];
    const float* w0 = &att0[h * DH];
    const float* w1 = &att1[h * DH];
    float s0 = 0.f, s1 = 0.f;
    #pragma unroll
    for (int k = 0; k < 16; k++) {
        unsigned v = vw[k];
        float v0 = bflo(v), v1 = bfhi(v);
        s0 += v0 * w0[2 * k] + v1 * w0[2 * k + 1];
        s1 += v0 * w1[2 * k] + v1 * w1[2 * k + 1];
    }
    a_self[idx]  = s0 + attb0[h];
    a_neigh[idx] = s1 + attb1[h];
}

// ---------------- CSR build ----------------
__global__ void k_hist(const int* __restrict__ rows, int* __restrict__ cnt) {
    int e = blockIdx.x * 256 + threadIdx.x;
    if (e < N_EDGES) atomicAdd(&cnt[rows[e]], 1);
}

// scan stage A: per-block sum of 256 cnt entries
__global__ __launch_bounds__(256)
void k_scanA(const int* __restrict__ cnt, int* __restrict__ bsum) {
    int t = threadIdx.x;
    int idx = blockIdx.x * 256 + t;
    int v = (idx < N_NODES) ? cnt[idx] : 0;
    #pragma unroll
    for (int d = 1; d < 64; d <<= 1) v += __shfl_xor(v, d, 64);
    __shared__ int ws[4];
    if ((t & 63) == 0) ws[t >> 6] = v;
    __syncthreads();
    if (t == 0) bsum[blockIdx.x] = ws[0] + ws[1] + ws[2] + ws[3];
}

// scan stage B: single block scans the 391 block sums -> exclusive bases
__global__ __launch_bounds__(512)
void k_scanB(const int* __restrict__ bsum, int* __restrict__ bbase, int* __restrict__ offs) {
    __shared__ int sh[512];
    int t = threadIdx.x;
    int v = (t < NBLK) ? bsum[t] : 0;
    sh[t] = v;
    __syncthreads();
    for (int d = 1; d < 512; d <<= 1) {
        int x = (t >= d) ? sh[t - d] : 0;
        __syncthreads();
        sh[t] += x;
        __syncthreads();
    }
    if (t < NBLK) bbase[t] = sh[t] - v;     // exclusive base
    if (t == 0) offs[N_NODES] = N_EDGES;
}

// scan stage C: per-block exclusive scan + base -> offs
__global__ __launch_bounds__(256)
void k_scanC(const int* __restrict__ cnt, const int* __restrict__ bbase,
             int* __restrict__ offs) {
    int t = threadIdx.x;
    int lane = t & 63;
    int w = t >> 6;
    int idx = blockIdx.x * 256 + t;
    int v = (idx < N_NODES) ? cnt[idx] : 0;
    int incl = v;
    #pragma unroll
    for (int d = 1; d < 64; d <<= 1) {
        int x = __shfl_up(incl, d, 64);
        if (lane >= d) incl += x;
    }
    __shared__ int wsum[4];
    if (lane == 63) wsum[w] = incl;
    __syncthreads();
    int wbase = 0;
    #pragma unroll
    for (int i = 0; i < 4; i++) if (i < w) wbase += wsum[i];
    if (idx < N_NODES) offs[idx] = incl - v + wbase + bbase[blockIdx.x];
}

// K5: fill CSR with packed {col, adj_val} (single 8B scattered store per edge).
// cursor pre-initialized to offs (D2D copy) -> atomicAdd yields absolute slot.
__global__ void k_fill(const int* __restrict__ rows, const int* __restrict__ cols,
                       const float* __restrict__ adj_vals,
                       int* __restrict__ cursor, int2* __restrict__ cav) {
    int e = blockIdx.x * 256 + threadIdx.x;
    if (e >= N_EDGES) return;
    int r = rows[e];
    int slot = atomicAdd(&cursor[r], 1);
    int2 p;
    p.x = cols[e];
    p.y = __float_as_int(adj_vals[e]);
    cav[slot] = p;
}

// ---------------- K6: per-node gather (alpha inline) + both row-norms + add -------
// one wave per node; lane owns features 2*lane, 2*lane+1 (head h = lane>>4)
__global__ __launch_bounds__(256)
void k_final(const float* __restrict__ comb_self, const unsigned short* __restrict__ vwb,
             const int2* __restrict__ cav, const float* __restrict__ a_self,
             const float* __restrict__ a_neigh,
             const int* __restrict__ offs, const float* __restrict__ b1,
             const float* __restrict__ off0, const float* __restrict__ sc0,
             const float* __restrict__ off1, const float* __restrict__ sc1,
             float* __restrict__ out) {
    int wave = threadIdx.x >> 6;
    int lane = threadIdx.x & 63;
    int n = blockIdx.x * 4 + wave;
    if (n >= N_NODES) return;
    int h = lane >> 4;
    int f0 = lane * 2;
    int f1 = f0 + 1;

    float as_ = a_self[n * 4 + h];
    int lo = offs[n], hi = offs[n + 1];
    float acc0 = 0.f, acc1 = 0.f;

#define BODY(I) { \
        int2 p_ = cav[(I)]; \
        int c_ = p_.x; \
        float av_ = __int_as_float(p_.y); \
        float an_ = a_neigh[c_ * 4 + h]; \
        unsigned v_ = *(const unsigned*)&vwb[(size_t)c_ * 128 + f0]; \
        float al_ = fmaxf(an_ + as_, 0.f) * av_; \
        acc0 += al_ * bflo(v_); \
        acc1 += al_ * bfhi(v_); }

    int i = lo;
    for (; i + 4 <= hi; i += 4) { BODY(i) BODY(i + 1) BODY(i + 2) BODY(i + 3) }
    for (; i < hi; i++) BODY(i)
#undef BODY

    // ret_neigh = relu(agg) + b1 (bias outside relu), then row-norm
    float x0 = fmaxf(acc0, 0.f) + b1[f0];
    float x1 = fmaxf(acc1, 0.f) + b1[f1];
    float s = x0 + x1;
    #pragma unroll
    for (int d = 32; d > 0; d >>= 1) s += __shfl_xor(s, d, 64);
    float mean = s * (1.f / 128.f);
    float d0 = x0 - mean, d1 = x1 - mean;
    float q = d0 * d0 + d1 * d1;
    #pragma unroll
    for (int d = 32; d > 0; d >>= 1) q += __shfl_xor(q, d, 64);
    float rinv = rsqrtf(q * (1.f / 128.f) + EPS);
    float y0 = sc1[f0] * d0 * rinv + off1[f0];
    float y1 = sc1[f1] * d1 * rinv + off1[f1];

    // self path (already relu(vecs@W0+b0)), row-norm
    float2 u = *(const float2*)&comb_self[(size_t)n * 128 + f0];
    float s2 = u.x + u.y;
    #pragma unroll
    for (int d = 32; d > 0; d >>= 1) s2 += __shfl_xor(s2, d, 64);
    float m2 = s2 * (1.f / 128.f);
    float e0 = u.x - m2, e1 = u.y - m2;
    float q2 = e0 * e0 + e1 * e1;
    #pragma unroll
    for (int d = 32; d > 0; d >>= 1) q2 += __shfl_xor(q2, d, 64);
    float rinv2 = rsqrtf(q2 * (1.f / 128.f) + EPS);
    float z0 = sc0[f0] * e0 * rinv2 + off0[f0];
    float z1 = sc0[f1] * e1 * rinv2 + off0[f1];

    *(float2*)&out[(size_t)n * 128 + f0] = make_float2(y0 + z0, y1 + z1);
}

extern "C" void kernel_launch(void* const* d_in, const int* in_sizes, int n_in,
                              void* d_out, int out_size, void* d_ws, size_t ws_size,
                              hipStream_t stream) {
    const float* vecs     = (const float*)d_in[0];
    const float* adj_vals = (const float*)d_in[1];
    const float* W0       = (const float*)d_in[2];
    const float* b0       = (const float*)d_in[3];
    const float* W1       = (const float*)d_in[4];
    const float* b1       = (const float*)d_in[5];
    const float* att0     = (const float*)d_in[6];
    const float* att1     = (const float*)d_in[7];
    const float* att_b0   = (const float*)d_in[8];
    const float* att_b1   = (const float*)d_in[9];
    const float* off0     = (const float*)d_in[10];
    const float* sc0      = (const float*)d_in[11];
    const float* off1     = (const float*)d_in[12];
    const float* sc1      = (const float*)d_in[13];
    const int*   adj_rows = (const int*)d_in[14];
    const int*   adj_cols = (const int*)d_in[15];
    float* out = (float*)d_out;

    char* ws = (char*)d_ws;
    size_t o = 0;
    auto alloc = [&](size_t bytes) {
        char* p = ws + o;
        o += (bytes + 255) & ~(size_t)255;
        return p;
    };
    const int MPAD = 100032;                                        // 64-aligned M
    // vecsb (25.61 MB) dead after k_gemm; cav (12.8 MB) born at k_fill -> alias.
    unsigned short* vecsb = (unsigned short*)alloc((size_t)MPAD * 128 * 2);
    unsigned short* Wtb   = (unsigned short*)alloc((size_t)256 * 128 * 2);
    float* comb_self      = (float*)alloc((size_t)N_NODES * 128 * 4);
    unsigned short* vwb   = (unsigned short*)alloc((size_t)N_NODES * 128 * 2);
    float* a_self         = (float*)alloc((size_t)N_NODES * NH * 4);
    float* a_neigh        = (float*)alloc((size_t)N_NODES * NH * 4);
    int*   cnt            = (int*)alloc((size_t)N_NODES * 4);       // hist; later cursor
    int*   offs           = (int*)alloc((size_t)(N_NODES + 1) * 4);
    int*   bsum           = (int*)alloc((size_t)NBLK * 4);
    int*   bbase          = (int*)alloc((size_t)NBLK * 4);
    int2*  cav            = (int2*)vecsb;   // alias: disjoint lifetime, 12.8MB <= 25.61MB

    k_cast<<<(N_NODES * 128 / 8 + 255) / 256, 256, 0, stream>>>(vecs, vecsb);
    k_build_wtb<<<128, 256, 0, stream>>>(W0, W1, Wtb);

    dim3 g2(2, MPAD / 64);
    k_gemm<<<g2, 256, 0, stream>>>(vecsb, Wtb, b0, comb_self, vwb);

    k_att<<<(N_NODES * NH + 255) / 256, 256, 0, stream>>>(vwb, att0, att1, att_b0, att_b1,
                                                          a_self, a_neigh);

    hipMemsetAsync(cnt, 0, (size_t)N_NODES * 4, stream);
    k_hist<<<(N_EDGES + 255) / 256, 256, 0, stream>>>(adj_rows, cnt);
    k_scanA<<<NBLK, 256, 0, stream>>>(cnt, bsum);
    k_scanB<<<1, 512, 0, stream>>>(bsum, bbase, offs);
    k_scanC<<<NBLK, 256, 0, stream>>>(cnt, bbase, offs);
    // cursor := offs (cnt buffer is dead after scanC; reuse it as cursor)
    hipMemcpyAsync(cnt, offs, (size_t)N_NODES * 4, hipMemcpyDeviceToDevice, stream);
    k_fill<<<(N_EDGES + 255) / 256, 256, 0, stream>>>(adj_rows, adj_cols, adj_vals,
                                                      cnt, cav);

    k_final<<<(N_NODES + 3) / 4, 256, 0, stream>>>(comb_self, vwb, cav, a_self, a_neigh,
                                                   offs, b1, off0, sc0, off1, sc1, out);
}

// Round 8
// 353.773 us; speedup vs baseline: 2.3682x; 1.3236x over previous
//
#include <hip/hip_runtime.h>

#define N_NODES 100000
#define N_EDGES 1600000
#define DIN 128
#define DOUT 128
#define NH 4
#define DH 32
#define EPS 1e-9f

// two-level counting sort geometry
#define NBUK 256        // coarse buckets: bucket = row >> 9 (512 rows); 196 used
#define NBUK_USED 196
#define CBLK 784        // coarse blocks
#define EPB  2048       // edges per coarse block (784*2048 >= 1.6M)
#define COLMASK 0x1FFFF

typedef short bf16x8 __attribute__((ext_vector_type(8)));
typedef float f32x4 __attribute__((ext_vector_type(4)));

__device__ inline unsigned short f2bf(float x) {
    unsigned u = __float_as_uint(x);
    unsigned r = (u + 0x7fffu + ((u >> 16) & 1u)) >> 16;
    return (unsigned short)r;
}
__device__ inline float bflo(unsigned v) { return __uint_as_float(v << 16); }
__device__ inline float bfhi(unsigned v) { return __uint_as_float(v & 0xffff0000u); }

// ---------------- K0: cast vecs f32 -> bf16 ----------------
__global__ void k_cast(const float* __restrict__ in, unsigned short* __restrict__ out) {
    int t = blockIdx.x * 256 + threadIdx.x;        // 8 floats per thread
    const float4* p = (const float4*)(in + (size_t)t * 8);
    float4 a = p[0], b = p[1];
    unsigned short o[8] = {f2bf(a.x), f2bf(a.y), f2bf(a.z), f2bf(a.w),
                           f2bf(b.x), f2bf(b.y), f2bf(b.z), f2bf(b.w)};
    *(bf16x8*)(out + (size_t)t * 8) = *(bf16x8*)o;
}

// ---------------- K1: build W^T bf16 [256][128] ----------------
__global__ void k_build_wtb(const float* __restrict__ W0, const float* __restrict__ W1,
                            unsigned short* __restrict__ Wtb) {
    int idx = blockIdx.x * 256 + threadIdx.x;      // 0..32767
    int j = idx >> 7;                              // output col 0..255
    int k = idx & 127;                             // input dim
    float v;
    if (j < 128) v = W0[k * 128 + j];
    else {
        int f = j - 128;
        v = W1[(f >> 5) * (DIN * DH) + k * DH + (f & 31)];
    }
    Wtb[j * 128 + k] = f2bf(v);
}

// ---------------- K2: MFMA GEMM  [M x 256] = vecsb[M x 128] @ W ----------------
__global__ __launch_bounds__(256)
void k_gemm(const unsigned short* __restrict__ A, const unsigned short* __restrict__ B,
            const float* __restrict__ b0, float* __restrict__ comb_self,
            unsigned short* __restrict__ vwb) {
    __shared__ short As[64][136];
    __shared__ short Bs[128][136];
    int tid = threadIdx.x;
    int wave = tid >> 6;
    int lane = tid & 63;
    int m0 = blockIdx.y * 64;
    int j0 = blockIdx.x * 128;

    #pragma unroll
    for (int it = 0; it < 4; it++) {
        int ch = tid + it * 256;
        int row = ch >> 4, k8 = (ch & 15) << 3;
        *(bf16x8*)&As[row][k8] = *(const bf16x8*)&A[(size_t)(m0 + row) * 128 + k8];
    }
    #pragma unroll
    for (int it = 0; it < 8; it++) {
        int ch = tid + it * 256;
        int j = ch >> 4, k8 = (ch & 15) << 3;
        *(bf16x8*)&Bs[j][k8] = *(const bf16x8*)&B[(size_t)(j0 + j) * 128 + k8];
    }
    __syncthreads();

    int lrow = lane & 15;
    int g8 = (lane >> 4) << 3;
    f32x4 acc[4][2] = {};
    #pragma unroll
    for (int kk = 0; kk < 4; kk++) {
        int kb = kk * 32 + g8;
        bf16x8 a[4], b[2];
        #pragma unroll
        for (int r = 0; r < 4; r++) a[r] = *(bf16x8*)&As[r * 16 + lrow][kb];
        #pragma unroll
        for (int q = 0; q < 2; q++) b[q] = *(bf16x8*)&Bs[wave * 32 + q * 16 + lrow][kb];
        #pragma unroll
        for (int r = 0; r < 4; r++)
            #pragma unroll
            for (int q = 0; q < 2; q++)
                acc[r][q] = __builtin_amdgcn_mfma_f32_16x16x32_bf16(a[r], b[q], acc[r][q], 0, 0, 0);
    }

    int rbase = (lane >> 4) << 2;
    #pragma unroll
    for (int r = 0; r < 4; r++) {
        #pragma unroll
        for (int q = 0; q < 2; q++) {
            int gcol = j0 + wave * 32 + q * 16 + lrow;
            #pragma unroll
            for (int reg = 0; reg < 4; reg++) {
                int grow = m0 + r * 16 + rbase + reg;
                if (grow >= N_NODES) continue;
                float v = acc[r][q][reg];
                if (gcol < 128) {
                    comb_self[(size_t)grow * 128 + gcol] = fmaxf(v + b0[gcol], 0.f);
                } else {
                    vwb[(size_t)grow * 128 + (gcol - 128)] = f2bf(v);
                }
            }
        }
    }
}

// ---------------- K3: per-(node,head) attention logits ----------------
__global__ void k_att(const unsigned short* __restrict__ vwb, const float* __restrict__ att0,
                      const float* __restrict__ att1, const float* __restrict__ attb0,
                      const float* __restrict__ attb1,
                      float* __restrict__ a_self, float* __restrict__ a_neigh) {
    int idx = blockIdx.x * 256 + threadIdx.x;
    if (idx >= N_NODES * NH) return;
    int n = idx >> 2;
    int h = idx & 3;
    const unsigned* vw = (const unsigned*)&vwb[(size_t)n * 128 + h * 32];
    const float* w0 = &att0[h * DH];
    const float* w1 = &att1[h * DH];
    float s0 = 0.f, s1 = 0.f;
    #pragma unroll
    for (int k = 0; k < 16; k++) {
        unsigned v = vw[k];
        float v0 = bflo(v), v1 = bfhi(v);
        s0 += v0 * w0[2 * k] + v1 * w0[2 * k + 1];
        s1 += v0 * w1[2 * k] + v1 * w1[2 * k + 1];
    }
    a_self[idx]  = s0 + attb0[h];
    a_neigh[idx] = s1 + attb1[h];
}

// ======== atomic-free CSR build: two-level counting sort ========

// S1: per-block coarse histogram (LDS atomics only)
__global__ __launch_bounds__(256)
void k_bh(const int* __restrict__ rows, int* __restrict__ H) {
    __shared__ int h[NBUK];
    int t = threadIdx.x, b = blockIdx.x;
    h[t] = 0;
    __syncthreads();
    int e0 = b * EPB;
    int lim = min(EPB, N_EDGES - e0);
    for (int i = t; i < lim; i += 256)
        atomicAdd(&h[rows[e0 + i] >> 9], 1);
    __syncthreads();
    H[b * NBUK + t] = h[t];
}

// S2: per-bucket exclusive scan across the CBLK blocks
__global__ __launch_bounds__(1024)
void k_bs(const int* __restrict__ H, int* __restrict__ BS, int* __restrict__ total) {
    __shared__ int sh[1024];
    int t = threadIdx.x, bk = blockIdx.x;
    int v = (t < CBLK) ? H[t * NBUK + bk] : 0;
    sh[t] = v;
    __syncthreads();
    for (int d = 1; d < 1024; d <<= 1) {
        int x = (t >= d) ? sh[t - d] : 0;
        __syncthreads();
        sh[t] += x;
        __syncthreads();
    }
    if (t < CBLK) BS[bk * CBLK + t] = sh[t] - v;
    if (t == 1023) total[bk] = sh[1023];
}

// S3: scan bucket totals -> bucket bases (single block)
__global__ __launch_bounds__(256)
void k_ts(const int* __restrict__ total, int* __restrict__ bb, int* __restrict__ offs) {
    __shared__ int sh[256];
    int t = threadIdx.x;
    int v = total[t];
    sh[t] = v;
    __syncthreads();
    for (int d = 1; d < 256; d <<= 1) {
        int x = (t >= d) ? sh[t - d] : 0;
        __syncthreads();
        sh[t] += x;
        __syncthreads();
    }
    bb[t] = sh[t] - v;
    if (t == 255) { bb[256] = sh[255]; offs[N_NODES] = sh[255]; }
}

// S4: coarse scatter of packed {col | rowlow<<17, val} records, bucket-grouped.
// Runs per (block,bucket) are contiguous & written within one block's lifetime
// -> L2 write-combining works (unlike the old random scatter).
__global__ __launch_bounds__(256)
void k_cscat(const int* __restrict__ rows, const int* __restrict__ cols,
             const float* __restrict__ vals, const int* __restrict__ bb,
             const int* __restrict__ BS, int2* __restrict__ T) {
    __shared__ int cur[NBUK];
    int t = threadIdx.x, b = blockIdx.x;
    cur[t] = 0;
    __syncthreads();
    int e0 = b * EPB;
    int lim = min(EPB, N_EDGES - e0);
    for (int i = t; i < lim; i += 256) {
        int e = e0 + i;
        int r = rows[e];
        int bk = r >> 9;
        int rank = atomicAdd(&cur[bk], 1);
        int dest = bb[bk] + BS[bk * CBLK + b] + rank;
        int2 p;
        p.x = cols[e] | ((r & 511) << 17);
        p.y = __float_as_int(vals[e]);
        T[dest] = p;
    }
}

// S5: fine pass, one block per bucket (512 rows): per-row counts -> offs,
// then permute records into exact CSR order (all traffic L2-local).
__global__ __launch_bounds__(512)
void k_fine(const int2* __restrict__ T, const int* __restrict__ bb,
            int* __restrict__ offs, int2* __restrict__ cav) {
    __shared__ int cnt[512], rb[512], cur[512], wsum[8];
    int t = threadIdx.x, b = blockIdx.x;
    int base = bb[b];
    int m = bb[b + 1] - base;
    cnt[t] = 0;
    cur[t] = 0;
    __syncthreads();
    for (int i = t; i < m; i += 512)
        atomicAdd(&cnt[(T[base + i].x >> 17) & 511], 1);
    __syncthreads();
    // block-wide exclusive scan of cnt[512]
    int lane = t & 63, w = t >> 6;
    int v = cnt[t];
    int incl = v;
    #pragma unroll
    for (int d = 1; d < 64; d <<= 1) {
        int x = __shfl_up(incl, d, 64);
        if (lane >= d) incl += x;
    }
    if (lane == 63) wsum[w] = incl;
    __syncthreads();
    int wb = 0;
    #pragma unroll
    for (int i = 0; i < 8; i++) if (i < w) wb += wsum[i];
    rb[t] = incl - v + wb;
    int rg = b * 512 + t;
    if (rg < N_NODES) offs[rg] = base + rb[t];
    __syncthreads();
    for (int i = t; i < m; i += 512) {
        int2 p = T[base + i];
        int r = (p.x >> 17) & 511;
        int k = atomicAdd(&cur[r], 1);
        cav[base + rb[r] + k] = p;
    }
}

// ---------------- K6: per-node gather (alpha inline) + both row-norms + add -------
__global__ __launch_bounds__(256)
void k_final(const float* __restrict__ comb_self, const unsigned short* __restrict__ vwb,
             const int2* __restrict__ cav, const float* __restrict__ a_self,
             const float* __restrict__ a_neigh,
             const int* __restrict__ offs, const float* __restrict__ b1,
             const float* __restrict__ off0, const float* __restrict__ sc0,
             const float* __restrict__ off1, const float* __restrict__ sc1,
             float* __restrict__ out) {
    int wave = threadIdx.x >> 6;
    int lane = threadIdx.x & 63;
    int n = blockIdx.x * 4 + wave;
    if (n >= N_NODES) return;
    int h = lane >> 4;
    int f0 = lane * 2;
    int f1 = f0 + 1;

    float as_ = a_self[n * 4 + h];
    int lo = offs[n], hi = offs[n + 1];
    float acc0 = 0.f, acc1 = 0.f;

#define BODY(I) { \
        int2 p_ = cav[(I)]; \
        int c_ = p_.x & COLMASK; \
        float av_ = __int_as_float(p_.y); \
        float an_ = a_neigh[c_ * 4 + h]; \
        unsigned v_ = *(const unsigned*)&vwb[(size_t)c_ * 128 + f0]; \
        float al_ = fmaxf(an_ + as_, 0.f) * av_; \
        acc0 += al_ * bflo(v_); \
        acc1 += al_ * bfhi(v_); }

    int i = lo;
    for (; i + 4 <= hi; i += 4) { BODY(i) BODY(i + 1) BODY(i + 2) BODY(i + 3) }
    for (; i < hi; i++) BODY(i)
#undef BODY

    float x0 = fmaxf(acc0, 0.f) + b1[f0];
    float x1 = fmaxf(acc1, 0.f) + b1[f1];
    float s = x0 + x1;
    #pragma unroll
    for (int d = 32; d > 0; d >>= 1) s += __shfl_xor(s, d, 64);
    float mean = s * (1.f / 128.f);
    float d0 = x0 - mean, d1 = x1 - mean;
    float q = d0 * d0 + d1 * d1;
    #pragma unroll
    for (int d = 32; d > 0; d >>= 1) q += __shfl_xor(q, d, 64);
    float rinv = rsqrtf(q * (1.f / 128.f) + EPS);
    float y0 = sc1[f0] * d0 * rinv + off1[f0];
    float y1 = sc1[f1] * d1 * rinv + off1[f1];

    float2 u = *(const float2*)&comb_self[(size_t)n * 128 + f0];
    float s2 = u.x + u.y;
    #pragma unroll
    for (int d = 32; d > 0; d >>= 1) s2 += __shfl_xor(s2, d, 64);
    float m2 = s2 * (1.f / 128.f);
    float e0 = u.x - m2, e1 = u.y - m2;
    float q2 = e0 * e0 + e1 * e1;
    #pragma unroll
    for (int d = 32; d > 0; d >>= 1) q2 += __shfl_xor(q2, d, 64);
    float rinv2 = rsqrtf(q2 * (1.f / 128.f) + EPS);
    float z0 = sc0[f0] * e0 * rinv2 + off0[f0];
    float z1 = sc0[f1] * e1 * rinv2 + off0[f1];

    *(float2*)&out[(size_t)n * 128 + f0] = make_float2(y0 + z0, y1 + z1);
}

extern "C" void kernel_launch(void* const* d_in, const int* in_sizes, int n_in,
                              void* d_out, int out_size, void* d_ws, size_t ws_size,
                              hipStream_t stream) {
    const float* vecs     = (const float*)d_in[0];
    const float* adj_vals = (const float*)d_in[1];
    const float* W0       = (const float*)d_in[2];
    const float* b0       = (const float*)d_in[3];
    const float* W1       = (const float*)d_in[4];
    const float* b1       = (const float*)d_in[5];
    const float* att0     = (const float*)d_in[6];
    const float* att1     = (const float*)d_in[7];
    const float* att_b0   = (const float*)d_in[8];
    const float* att_b1   = (const float*)d_in[9];
    const float* off0     = (const float*)d_in[10];
    const float* sc0      = (const float*)d_in[11];
    const float* off1     = (const float*)d_in[12];
    const float* sc1      = (const float*)d_in[13];
    const int*   adj_rows = (const int*)d_in[14];
    const int*   adj_cols = (const int*)d_in[15];
    float* out = (float*)d_out;

    char* ws = (char*)d_ws;
    size_t o = 0;
    auto alloc = [&](size_t bytes) {
        char* p = ws + o;
        o += (bytes + 255) & ~(size_t)255;
        return p;
    };
    const int MPAD = 100032;                                        // 64-aligned M
    // vecsb (25.61 MB) dead after k_gemm; T (12.8) + cav (12.8) alias into it.
    unsigned short* vecsb = (unsigned short*)alloc((size_t)MPAD * 128 * 2);
    unsigned short* Wtb   = (unsigned short*)alloc((size_t)256 * 128 * 2);
    float* comb_self      = (float*)alloc((size_t)N_NODES * 128 * 4);
    unsigned short* vwb   = (unsigned short*)alloc((size_t)N_NODES * 128 * 2);
    float* a_self         = (float*)alloc((size_t)N_NODES * NH * 4);
    float* a_neigh        = (float*)alloc((size_t)N_NODES * NH * 4);
    int*   offs           = (int*)alloc((size_t)(N_NODES + 1) * 4);
    int*   H              = (int*)alloc((size_t)CBLK * NBUK * 4);
    int*   BS             = (int*)alloc((size_t)NBUK * CBLK * 4);
    int*   total          = (int*)alloc((size_t)NBUK * 4);
    int*   bb             = (int*)alloc((size_t)(NBUK + 1) * 4);
    int2*  T              = (int2*)vecsb;                            // 12.8 MB
    int2*  cav            = (int2*)(vecsb + (size_t)N_EDGES * 4);    // +12.8 MB (shorts)

    k_cast<<<(N_NODES * 128 / 8 + 255) / 256, 256, 0, stream>>>(vecs, vecsb);
    k_build_wtb<<<128, 256, 0, stream>>>(W0, W1, Wtb);

    dim3 g2(2, MPAD / 64);
    k_gemm<<<g2, 256, 0, stream>>>(vecsb, Wtb, b0, comb_self, vwb);

    k_att<<<(N_NODES * NH + 255) / 256, 256, 0, stream>>>(vwb, att0, att1, att_b0, att_b1,
                                                          a_self, a_neigh);

    // CSR build (no global atomics)
    k_bh<<<CBLK, 256, 0, stream>>>(adj_rows, H);
    k_bs<<<NBUK, 1024, 0, stream>>>(H, BS, total);
    k_ts<<<1, 256, 0, stream>>>(total, bb, offs);
    k_cscat<<<CBLK, 256, 0, stream>>>(adj_rows, adj_cols, adj_vals, bb, BS, T);
    k_fine<<<NBUK_USED, 512, 0, stream>>>(T, bb, offs, cav);

    k_final<<<(N_NODES + 3) / 4, 256, 0, stream>>>(comb_self, vwb, cav, a_self, a_neigh,
                                                   offs, b1, off0, sc0, off1, sc1, out);
}

// Round 9
// 338.349 us; speedup vs baseline: 2.4762x; 1.0456x over previous
//
#include <hip/hip_runtime.h>

#define N_NODES 100000
#define N_EDGES 1600000
#define DIN 128
#define DOUT 128
#define NH 4
#define DH 32
#define EPS 1e-9f

// two-level counting sort geometry
#define NBUK 256        // coarse buckets: bucket = row >> 9 (512 rows); 196 used
#define NBUK_USED 196
#define CBLK 784        // coarse blocks
#define EPB  2048       // edges per coarse block (784*2048 >= 1.6M)
#define COLMASK 0x1FFFF

typedef short bf16x8 __attribute__((ext_vector_type(8)));
typedef float f32x4 __attribute__((ext_vector_type(4)));

__device__ inline unsigned short f2bf(float x) {
    unsigned u = __float_as_uint(x);
    unsigned r = (u + 0x7fffu + ((u >> 16) & 1u)) >> 16;
    return (unsigned short)r;
}
__device__ inline float bflo(unsigned v) { return __uint_as_float(v << 16); }
__device__ inline float bfhi(unsigned v) { return __uint_as_float(v & 0xffff0000u); }

// ---------------- K1: build W^T bf16 [256][128] ----------------
__global__ void k_build_wtb(const float* __restrict__ W0, const float* __restrict__ W1,
                            unsigned short* __restrict__ Wtb) {
    int idx = blockIdx.x * 256 + threadIdx.x;      // 0..32767
    int j = idx >> 7;                              // output col 0..255
    int k = idx & 127;                             // input dim
    float v;
    if (j < 128) v = W0[k * 128 + j];
    else {
        int f = j - 128;
        v = W1[(f >> 5) * (DIN * DH) + k * DH + (f & 31)];
    }
    Wtb[j * 128 + k] = f2bf(v);
}

// ---------------- K2: MFMA GEMM + fused cast + fused attention logits ----------
// A read as f32 (cvt during staging). x=0 tile -> comb_self (bf16, relu(x+b0));
// x=1 tile -> vwb (bf16) + a_self/a_neigh from f32 accumulators (wave w == head w).
__global__ __launch_bounds__(256)
void k_gemm(const float* __restrict__ A, const unsigned short* __restrict__ B,
            const float* __restrict__ b0,
            const float* __restrict__ att0, const float* __restrict__ att1,
            const float* __restrict__ attb0, const float* __restrict__ attb1,
            unsigned short* __restrict__ comb_selfb, unsigned short* __restrict__ vwb,
            float* __restrict__ a_self, float* __restrict__ a_neigh) {
    __shared__ short As[64][136];
    __shared__ short Bs[128][136];
    int tid = threadIdx.x;
    int wave = tid >> 6;
    int lane = tid & 63;
    int m0 = blockIdx.y * 64;
    int j0 = blockIdx.x * 128;

    // stage A from f32, convert to bf16 (rows >= N zero-filled)
    #pragma unroll
    for (int it = 0; it < 4; it++) {
        int ch = tid + it * 256;
        int row = ch >> 4, k8 = (ch & 15) << 3;
        int gr = m0 + row;
        float4 lo = make_float4(0.f, 0.f, 0.f, 0.f), hi = lo;
        if (gr < N_NODES) {
            const float* src = &A[(size_t)gr * 128 + k8];
            lo = *(const float4*)src;
            hi = *(const float4*)(src + 4);
        }
        unsigned short o[8] = {f2bf(lo.x), f2bf(lo.y), f2bf(lo.z), f2bf(lo.w),
                               f2bf(hi.x), f2bf(hi.y), f2bf(hi.z), f2bf(hi.w)};
        *(bf16x8*)&As[row][k8] = *(bf16x8*)o;
    }
    #pragma unroll
    for (int it = 0; it < 8; it++) {
        int ch = tid + it * 256;
        int j = ch >> 4, k8 = (ch & 15) << 3;
        *(bf16x8*)&Bs[j][k8] = *(const bf16x8*)&B[(size_t)(j0 + j) * 128 + k8];
    }
    __syncthreads();

    int lrow = lane & 15;
    int g8 = (lane >> 4) << 3;
    f32x4 acc[4][2] = {};
    #pragma unroll
    for (int kk = 0; kk < 4; kk++) {
        int kb = kk * 32 + g8;
        bf16x8 a[4], b[2];
        #pragma unroll
        for (int r = 0; r < 4; r++) a[r] = *(bf16x8*)&As[r * 16 + lrow][kb];
        #pragma unroll
        for (int q = 0; q < 2; q++) b[q] = *(bf16x8*)&Bs[wave * 32 + q * 16 + lrow][kb];
        #pragma unroll
        for (int r = 0; r < 4; r++)
            #pragma unroll
            for (int q = 0; q < 2; q++)
                acc[r][q] = __builtin_amdgcn_mfma_f32_16x16x32_bf16(a[r], b[q], acc[r][q], 0, 0, 0);
    }

    int rbase = (lane >> 4) << 2;
    // C/D: col = lane&15, row = (lane>>4)*4 + reg
    #pragma unroll
    for (int r = 0; r < 4; r++) {
        #pragma unroll
        for (int q = 0; q < 2; q++) {
            int gcol = j0 + wave * 32 + q * 16 + lrow;
            #pragma unroll
            for (int reg = 0; reg < 4; reg++) {
                int grow = m0 + r * 16 + rbase + reg;
                if (grow >= N_NODES) continue;
                float v = acc[r][q][reg];
                if (gcol < 128) {
                    comb_selfb[(size_t)grow * 128 + gcol] = f2bf(fmaxf(v + b0[gcol], 0.f));
                } else {
                    vwb[(size_t)grow * 128 + (gcol - 128)] = f2bf(v);
                }
            }
        }
    }

    // fused attention logits from f32 acc (x=1 tile: wave w holds head w cols)
    if (j0 == 128) {
        float w0q0 = att0[wave * 32 + lrow],      w0q1 = att0[wave * 32 + 16 + lrow];
        float w1q0 = att1[wave * 32 + lrow],      w1q1 = att1[wave * 32 + 16 + lrow];
        float ab0 = attb0[wave], ab1 = attb1[wave];
        #pragma unroll
        for (int r = 0; r < 4; r++) {
            float t0[4], t1[4];
            #pragma unroll
            for (int reg = 0; reg < 4; reg++) {
                t0[reg] = acc[r][0][reg] * w0q0 + acc[r][1][reg] * w0q1;
                t1[reg] = acc[r][0][reg] * w1q0 + acc[r][1][reg] * w1q1;
                #pragma unroll
                for (int d = 1; d < 16; d <<= 1) {
                    t0[reg] += __shfl_xor(t0[reg], d, 64);
                    t1[reg] += __shfl_xor(t1[reg], d, 64);
                }
            }
            if (lrow == 0) {
                #pragma unroll
                for (int reg = 0; reg < 4; reg++) {
                    int grow = m0 + r * 16 + rbase + reg;
                    if (grow < N_NODES) {
                        a_self[grow * 4 + wave]  = t0[reg] + ab0;
                        a_neigh[grow * 4 + wave] = t1[reg] + ab1;
                    }
                }
            }
        }
    }
}

// ======== atomic-free CSR build: two-level counting sort ========

// S1: per-block coarse histogram (LDS atomics only)
__global__ __launch_bounds__(256)
void k_bh(const int* __restrict__ rows, int* __restrict__ H) {
    __shared__ int h[NBUK];
    int t = threadIdx.x, b = blockIdx.x;
    h[t] = 0;
    __syncthreads();
    int e0 = b * EPB;
    int lim = min(EPB, N_EDGES - e0);
    for (int i = t; i < lim; i += 256)
        atomicAdd(&h[rows[e0 + i] >> 9], 1);
    __syncthreads();
    H[b * NBUK + t] = h[t];
}

// S2: per-bucket exclusive scan across the CBLK blocks
__global__ __launch_bounds__(1024)
void k_bs(const int* __restrict__ H, int* __restrict__ BS, int* __restrict__ total) {
    __shared__ int sh[1024];
    int t = threadIdx.x, bk = blockIdx.x;
    int v = (t < CBLK) ? H[t * NBUK + bk] : 0;
    sh[t] = v;
    __syncthreads();
    for (int d = 1; d < 1024; d <<= 1) {
        int x = (t >= d) ? sh[t - d] : 0;
        __syncthreads();
        sh[t] += x;
        __syncthreads();
    }
    if (t < CBLK) BS[bk * CBLK + t] = sh[t] - v;
    if (t == 1023) total[bk] = sh[1023];
}

// S3: scan bucket totals -> bucket bases (single block)
__global__ __launch_bounds__(256)
void k_ts(const int* __restrict__ total, int* __restrict__ bb, int* __restrict__ offs) {
    __shared__ int sh[256];
    int t = threadIdx.x;
    int v = total[t];
    sh[t] = v;
    __syncthreads();
    for (int d = 1; d < 256; d <<= 1) {
        int x = (t >= d) ? sh[t - d] : 0;
        __syncthreads();
        sh[t] += x;
        __syncthreads();
    }
    bb[t] = sh[t] - v;
    if (t == 255) { bb[256] = sh[255]; offs[N_NODES] = sh[255]; }
}

// S4: coarse scatter of packed {col | rowlow<<17, val} records, bucket-grouped
__global__ __launch_bounds__(256)
void k_cscat(const int* __restrict__ rows, const int* __restrict__ cols,
             const float* __restrict__ vals, const int* __restrict__ bb,
             const int* __restrict__ BS, int2* __restrict__ T) {
    __shared__ int cur[NBUK];
    int t = threadIdx.x, b = blockIdx.x;
    cur[t] = 0;
    __syncthreads();
    int e0 = b * EPB;
    int lim = min(EPB, N_EDGES - e0);
    for (int i = t; i < lim; i += 256) {
        int e = e0 + i;
        int r = rows[e];
        int bk = r >> 9;
        int rank = atomicAdd(&cur[bk], 1);
        int dest = bb[bk] + BS[bk * CBLK + b] + rank;
        int2 p;
        p.x = cols[e] | ((r & 511) << 17);
        p.y = __float_as_int(vals[e]);
        T[dest] = p;
    }
}

// S5: fine pass, one block per bucket (512 rows): per-row counts -> offs,
// then permute records into exact CSR order (all traffic L2-local)
__global__ __launch_bounds__(512)
void k_fine(const int2* __restrict__ T, const int* __restrict__ bb,
            int* __restrict__ offs, int2* __restrict__ cav) {
    __shared__ int cnt[512], rb[512], cur[512], wsum[8];
    int t = threadIdx.x, b = blockIdx.x;
    int base = bb[b];
    int m = bb[b + 1] - base;
    cnt[t] = 0;
    cur[t] = 0;
    __syncthreads();
    for (int i = t; i < m; i += 512)
        atomicAdd(&cnt[(T[base + i].x >> 17) & 511], 1);
    __syncthreads();
    int lane = t & 63, w = t >> 6;
    int v = cnt[t];
    int incl = v;
    #pragma unroll
    for (int d = 1; d < 64; d <<= 1) {
        int x = __shfl_up(incl, d, 64);
        if (lane >= d) incl += x;
    }
    if (lane == 63) wsum[w] = incl;
    __syncthreads();
    int wb = 0;
    #pragma unroll
    for (int i = 0; i < 8; i++) if (i < w) wb += wsum[i];
    rb[t] = incl - v + wb;
    int rg = b * 512 + t;
    if (rg < N_NODES) offs[rg] = base + rb[t];
    __syncthreads();
    for (int i = t; i < m; i += 512) {
        int2 p = T[base + i];
        int r = (p.x >> 17) & 511;
        int k = atomicAdd(&cur[r], 1);
        cav[base + rb[r] + k] = p;
    }
}

// ---------------- K6: per-node gather (alpha inline) + both row-norms + add -------
__global__ __launch_bounds__(256)
void k_final(const unsigned short* __restrict__ comb_selfb,
             const unsigned short* __restrict__ vwb,
             const int2* __restrict__ cav, const float* __restrict__ a_self,
             const float* __restrict__ a_neigh,
             const int* __restrict__ offs, const float* __restrict__ b1,
             const float* __restrict__ off0, const float* __restrict__ sc0,
             const float* __restrict__ off1, const float* __restrict__ sc1,
             float* __restrict__ out) {
    int wave = threadIdx.x >> 6;
    int lane = threadIdx.x & 63;
    int n = blockIdx.x * 4 + wave;
    if (n >= N_NODES) return;
    int h = lane >> 4;
    int f0 = lane * 2;
    int f1 = f0 + 1;

    float as_ = a_self[n * 4 + h];
    int lo = offs[n], hi = offs[n + 1];
    float acc0 = 0.f, acc1 = 0.f;

#define BODY(I) { \
        int2 p_ = cav[(I)]; \
        int c_ = p_.x & COLMASK; \
        float av_ = __int_as_float(p_.y); \
        float an_ = a_neigh[c_ * 4 + h]; \
        unsigned v_ = *(const unsigned*)&vwb[(size_t)c_ * 128 + f0]; \
        float al_ = fmaxf(an_ + as_, 0.f) * av_; \
        acc0 += al_ * bflo(v_); \
        acc1 += al_ * bfhi(v_); }

    int i = lo;
    for (; i + 4 <= hi; i += 4) { BODY(i) BODY(i + 1) BODY(i + 2) BODY(i + 3) }
    for (; i < hi; i++) BODY(i)
#undef BODY

    float x0 = fmaxf(acc0, 0.f) + b1[f0];
    float x1 = fmaxf(acc1, 0.f) + b1[f1];
    float s = x0 + x1;
    #pragma unroll
    for (int d = 32; d > 0; d >>= 1) s += __shfl_xor(s, d, 64);
    float mean = s * (1.f / 128.f);
    float d0 = x0 - mean, d1 = x1 - mean;
    float q = d0 * d0 + d1 * d1;
    #pragma unroll
    for (int d = 32; d > 0; d >>= 1) q += __shfl_xor(q, d, 64);
    float rinv = rsqrtf(q * (1.f / 128.f) + EPS);
    float y0 = sc1[f0] * d0 * rinv + off1[f0];
    float y1 = sc1[f1] * d1 * rinv + off1[f1];

    // self path (bf16 pre-norm relu(vecs@W0+b0)), row-norm in f32
    unsigned uu = *(const unsigned*)&comb_selfb[(size_t)n * 128 + f0];
    float ux = bflo(uu), uy = bfhi(uu);
    float s2 = ux + uy;
    #pragma unroll
    for (int d = 32; d > 0; d >>= 1) s2 += __shfl_xor(s2, d, 64);
    float m2 = s2 * (1.f / 128.f);
    float e0 = ux - m2, e1 = uy - m2;
    float q2 = e0 * e0 + e1 * e1;
    #pragma unroll
    for (int d = 32; d > 0; d >>= 1) q2 += __shfl_xor(q2, d, 64);
    float rinv2 = rsqrtf(q2 * (1.f / 128.f) + EPS);
    float z0 = sc0[f0] * e0 * rinv2 + off0[f0];
    float z1 = sc0[f1] * e1 * rinv2 + off0[f1];

    *(float2*)&out[(size_t)n * 128 + f0] = make_float2(y0 + z0, y1 + z1);
}

extern "C" void kernel_launch(void* const* d_in, const int* in_sizes, int n_in,
                              void* d_out, int out_size, void* d_ws, size_t ws_size,
                              hipStream_t stream) {
    const float* vecs     = (const float*)d_in[0];
    const float* adj_vals = (const float*)d_in[1];
    const float* W0       = (const float*)d_in[2];
    const float* b0       = (const float*)d_in[3];
    const float* W1       = (const float*)d_in[4];
    const float* b1       = (const float*)d_in[5];
    const float* att0     = (const float*)d_in[6];
    const float* att1     = (const float*)d_in[7];
    const float* att_b0   = (const float*)d_in[8];
    const float* att_b1   = (const float*)d_in[9];
    const float* off0     = (const float*)d_in[10];
    const float* sc0      = (const float*)d_in[11];
    const float* off1     = (const float*)d_in[12];
    const float* sc1      = (const float*)d_in[13];
    const int*   adj_rows = (const int*)d_in[14];
    const int*   adj_cols = (const int*)d_in[15];
    float* out = (float*)d_out;

    char* ws = (char*)d_ws;
    size_t o = 0;
    auto alloc = [&](size_t bytes) {
        char* p = ws + o;
        o += (bytes + 255) & ~(size_t)255;
        return p;
    };
    const int MPAD = 100032;                                        // 64-aligned M
    unsigned short* Wtb   = (unsigned short*)alloc((size_t)256 * 128 * 2);
    unsigned short* comb_selfb = (unsigned short*)alloc((size_t)N_NODES * 128 * 2);
    unsigned short* vwb   = (unsigned short*)alloc((size_t)N_NODES * 128 * 2);
    float* a_self         = (float*)alloc((size_t)N_NODES * NH * 4);
    float* a_neigh        = (float*)alloc((size_t)N_NODES * NH * 4);
    int*   offs           = (int*)alloc((size_t)(N_NODES + 1) * 4);
    int*   H              = (int*)alloc((size_t)CBLK * NBUK * 4);
    int*   BS             = (int*)alloc((size_t)NBUK * CBLK * 4);
    int*   total          = (int*)alloc((size_t)NBUK * 4);
    int*   bb             = (int*)alloc((size_t)(NBUK + 1) * 4);
    int2*  T              = (int2*)alloc((size_t)N_EDGES * 8);
    int2*  cav            = (int2*)alloc((size_t)N_EDGES * 8);

    k_build_wtb<<<128, 256, 0, stream>>>(W0, W1, Wtb);

    dim3 g2(2, MPAD / 64);
    k_gemm<<<g2, 256, 0, stream>>>(vecs, Wtb, b0, att0, att1, att_b0, att_b1,
                                   comb_selfb, vwb, a_self, a_neigh);

    // CSR build (no global atomics)
    k_bh<<<CBLK, 256, 0, stream>>>(adj_rows, H);
    k_bs<<<NBUK, 1024, 0, stream>>>(H, BS, total);
    k_ts<<<1, 256, 0, stream>>>(total, bb, offs);
    k_cscat<<<CBLK, 256, 0, stream>>>(adj_rows, adj_cols, adj_vals, bb, BS, T);
    k_fine<<<NBUK_USED, 512, 0, stream>>>(T, bb, offs, cav);

    k_final<<<(N_NODES + 3) / 4, 256, 0, stream>>>(comb_selfb, vwb, cav, a_self, a_neigh,
                                                   offs, b1, off0, sc0, off1, sc1, out);
}